// Round 5
// baseline (222.898 us; speedup 1.0000x reference)
//
#include <hip/hip_runtime.h>

#define BB 256
#define NN 4096
#define CC 16
#define WW 10
#define LL 4087  // N - W + 1
#define EPSF 1e-5f

// ws layout: pk [0, 524288) | counter @ 524288 | outraw [524352, 557120)

// ---------------- Kernel 0: pack + zero-pad weights, zero finish counter ----------------
// pk[n*16+c] = {Wr[c,n], Wi[c,n]}, zeros for n >= LL
__global__ __launch_bounds__(256) void pack_weights(const float* __restrict__ Wr,
                                                    const float* __restrict__ Wi,
                                                    float2* __restrict__ pk,
                                                    unsigned* __restrict__ counter) {
    int tg = blockIdx.x * 256 + threadIdx.x;  // [0, 65536)
    int n = tg >> 4, c = tg & 15;
    float2 v = make_float2(0.f, 0.f);
    if (n < LL) { v.x = Wr[c * LL + n]; v.y = Wi[c * LL + n]; }
    pk[tg] = v;
    if (tg == 0) *counter = 0u;  // ws is re-poisoned 0xAA before every launch
}

// ---------------- Kernel 1: fused stage1+2+3 (+BN by last block), one block per b ----------------
// 1024 threads = 64 tc (n-chunks of 64) x 16 c. Rolling 16-slot weight window,
// x read exactly once as float2. 16 waves/CU = 4 waves/SIMD for latency hiding.
template <bool PK, bool FUSE_BN>
__global__ __launch_bounds__(1024) void fused_main(const float* __restrict__ x,
                                                   const float2* __restrict__ pk,
                                                   const float* __restrict__ Wr,
                                                   const float* __restrict__ Wi,
                                                   const float* __restrict__ Wnl,
                                                   const float* __restrict__ Wor,
                                                   const float* __restrict__ Woi,
                                                   float* __restrict__ outraw,
                                                   unsigned* __restrict__ counter,
                                                   const float* __restrict__ gamma,
                                                   const float* __restrict__ beta,
                                                   float* __restrict__ out) {
    const int b = blockIdx.x;
    const int tid = threadIdx.x;
    const int tc = tid >> 4;   // 0..63
    const int c = tid & 15;
    const int n0 = tc * 64;

    const float2* __restrict__ x2 = (const float2*)x + (size_t)b * (NN * CC);

    float wr[16], wi[16];
    float fr[WW], fi[WW];
#pragma unroll
    for (int w = 0; w < WW; ++w) { fr[w] = 0.f; fi[w] = 0.f; }

    // prefill slots 15..7 with weights n0-1..n0-9 (zero if negative)
#pragma unroll
    for (int i = 1; i <= 9; ++i) {
        const int m = n0 - i;
        float vr = 0.f, vi = 0.f;
        if (PK) {
            if (m >= 0) { const float2 t = pk[m * 16 + c]; vr = t.x; vi = t.y; }
        } else {
            const int mc = m < 0 ? 0 : m;
            const float a = Wr[c * LL + mc], q = Wi[c * LL + mc];
            vr = (m >= 0) ? a : 0.f;
            vi = (m >= 0) ? q : 0.f;
        }
        wr[16 - i] = vr;
        wi[16 - i] = vi;
    }

#pragma unroll 1
    for (int g = 0; g < 4; ++g) {
        const int nb = n0 + g * 16;
#pragma unroll
        for (int p = 0; p < 16; ++p) {
            const int n = nb + p;
            float vr, vi;
            if (PK) {
                const float2 t = pk[n * 16 + c];
                vr = t.x; vi = t.y;
            } else {
                const int nc2 = (n < LL) ? n : (LL - 1);
                const float a = Wr[c * LL + nc2], q = Wi[c * LL + nc2];
                vr = (n < LL) ? a : 0.f;
                vi = (n < LL) ? q : 0.f;
            }
            const float2 xv = x2[n * 16 + c];
            wr[p] = vr;
            wi[p] = vi;
#pragma unroll
            for (int w = 0; w < WW; ++w) {
                fr[w] += xv.x * wr[(p - w) & 15];
                fi[w] += xv.y * wi[(p - w) & 15];
            }
        }
    }

    // reduce over tc: within a wave tc occupies lane bits 4..5 -> xor-reduce,
    // then 16 wave-partials via LDS.
#pragma unroll
    for (int w = 0; w < WW; ++w) {
        fr[w] += __shfl_xor(fr[w], 16);
        fr[w] += __shfl_xor(fr[w], 32);
        fi[w] += __shfl_xor(fi[w], 16);
        fi[w] += __shfl_xor(fi[w], 32);
    }
    __shared__ float red[16][320];
    __shared__ float F2[320];
    __shared__ float nls[320];
    const int lane = tid & 63, wave = tid >> 6;
    if (lane < 16) {  // lane == c for these lanes
#pragma unroll
        for (int w = 0; w < WW; ++w) {
            red[wave][lane * 20 + w] = fr[w];
            red[wave][lane * 20 + 10 + w] = fi[w];
        }
    }
    __syncthreads();
    if (tid < 320) {
        float s = 0.f;
#pragma unroll
        for (int k = 0; k < 16; ++k) s += red[k][tid];
        F2[tid] = s;  // slot = c*20 + j*10 + w  (j=0:real, 1:imag)
    }
    __syncthreads();
    // amplitude scaling
    if (tid < 160) {
        const int cc = tid / 10, w = tid % 10;
        const float a = F2[cc * 20 + w], q = F2[cc * 20 + 10 + w];
        const float amp = a * a + q * q;
        F2[cc * 20 + w] = a * amp;
        F2[cc * 20 + 10 + w] = q * amp;
    }
    __syncthreads();
    // nl[w,c,o] = sum_i tf[w,i] * Wnl[c,o,i]
    if (tid < 320) {
        const int cc = tid / 20, rem = tid % 20, o = rem / 10, w = rem % 10;
        const float* __restrict__ wn = Wnl + (cc * 2 + o) * 32;
        float acc = 0.f;
#pragma unroll
        for (int i = 0; i < 16; ++i) acc += F2[i * 20 + w] * wn[i];
#pragma unroll
        for (int i = 0; i < 16; ++i) acc += F2[i * 20 + 10 + w] * wn[16 + i];
        nls[tid] = acc;  // slot = c*20 + o*10 + w
    }
    __syncthreads();
    // raw out[b,c,o] = sum_w nl[w,c,o] * Wout_o[c,w]
    if (tid < 32) {
        const int cc = tid >> 1, o = tid & 1;
        const float* __restrict__ wo = (o == 0 ? Wor : Woi) + cc * WW;
        float acc = 0.f;
#pragma unroll
        for (int w = 0; w < WW; ++w) acc += nls[cc * 20 + o * 10 + w] * wo[w];
        outraw[b * 32 + cc * 2 + o] = acc;
    }

    if (!FUSE_BN) return;

    // ---- last-block BatchNorm finalizer (release/acquire via device-scope fence) ----
    __syncthreads();  // all 32 outraw stores retired (s_waitcnt vmcnt(0) before barrier)
    __shared__ int lastBlk;
    if (tid == 0) {
        __threadfence();  // release: write back local L2 so outraw is device-visible
        const unsigned prev = atomicAdd(counter, 1u);  // device-scope by default
        lastBlk = (prev == BB - 1) ? 1 : 0;
    }
    __syncthreads();
    if (!lastBlk) return;
    __threadfence();  // acquire: invalidate stale L1/L2 before reading other blocks' outraw

    // one wave per channel; lane handles 8 of the 512 (b,comp) values
    const int cch = wave;  // 0..15
    float v[8], s = 0.f, ss = 0.f;
#pragma unroll
    for (int k = 0; k < 8; ++k) {
        const int idx = lane + 64 * k;   // = b*2 + o
        const int bb = idx >> 1, o = idx & 1;
        v[k] = outraw[bb * 32 + cch * 2 + o];
        s += v[k];
        ss += v[k] * v[k];
    }
#pragma unroll
    for (int off = 32; off > 0; off >>= 1) {
        s += __shfl_xor(s, off);
        ss += __shfl_xor(ss, off);
    }
    const float mean = s * (1.f / 512.f);
    const float var = ss * (1.f / 512.f) - mean * mean;
    const float scale = gamma[cch] * rsqrtf(var + EPSF);
    const float sh = beta[cch];
#pragma unroll
    for (int k = 0; k < 8; ++k) {
        const int idx = lane + 64 * k;
        const int bb = idx >> 1, o = idx & 1;
        out[bb * 32 + cch * 2 + o] = (v[k] - mean) * scale + sh;
    }
}

// ---------------- Fallback BatchNorm (tiny-ws path only) ----------------
__global__ __launch_bounds__(256) void bnorm(float* __restrict__ out,
                                             const float* __restrict__ gamma,
                                             const float* __restrict__ beta) {
    const int c = blockIdx.x;   // [0,16)
    const int t = threadIdx.x;  // [0,256) == b
    const float v0 = out[t * 32 + c * 2 + 0];
    const float v1 = out[t * 32 + c * 2 + 1];
    float s = v0 + v1;
    float ss = v0 * v0 + v1 * v1;
#pragma unroll
    for (int off = 32; off > 0; off >>= 1) {
        s += __shfl_down(s, off, 64);
        ss += __shfl_down(ss, off, 64);
    }
    __shared__ float ls[8];
    const int wave = t >> 6, lane = t & 63;
    if (lane == 0) { ls[wave * 2] = s; ls[wave * 2 + 1] = ss; }
    __syncthreads();
    const float S = ls[0] + ls[2] + ls[4] + ls[6];
    const float SS = ls[1] + ls[3] + ls[5] + ls[7];
    const float mean = S * (1.f / 512.f);
    const float var = SS * (1.f / 512.f) - mean * mean;
    const float scale = gamma[c] * rsqrtf(var + EPSF);
    const float sh = beta[c];
    out[t * 32 + c * 2 + 0] = (v0 - mean) * scale + sh;
    out[t * 32 + c * 2 + 1] = (v1 - mean) * scale + sh;
}

extern "C" void kernel_launch(void* const* d_in, const int* in_sizes, int n_in,
                              void* d_out, int out_size, void* d_ws, size_t ws_size,
                              hipStream_t stream) {
    const float* x     = (const float*)d_in[0];
    const float* Wr    = (const float*)d_in[1];
    const float* Wi    = (const float*)d_in[2];
    const float* Wnl   = (const float*)d_in[3];
    const float* Wor   = (const float*)d_in[4];
    const float* Woi   = (const float*)d_in[5];
    const float* gamma = (const float*)d_in[6];
    const float* beta  = (const float*)d_in[7];
    float* out = (float*)d_out;

    char* ws = (char*)d_ws;
    float2*   pk      = (float2*)ws;                    // [0, 524288)
    unsigned* counter = (unsigned*)(ws + 524288);       // 4 B
    float*    outraw  = (float*)(ws + 524352);          // 32 KB
    const bool full = (ws_size >= 524352 + 32768);      // ws_size fixed -> same path every call

    if (full) {
        hipLaunchKernelGGL(pack_weights, dim3(256), dim3(256), 0, stream, Wr, Wi, pk, counter);
        hipLaunchKernelGGL((fused_main<true, true>), dim3(BB), dim3(1024), 0, stream,
                           x, pk, Wr, Wi, Wnl, Wor, Woi, outraw, counter, gamma, beta, out);
    } else {
        // tiny-ws fallback: raw results straight to d_out, separate BN in place
        hipLaunchKernelGGL((fused_main<false, false>), dim3(BB), dim3(1024), 0, stream,
                           x, pk, Wr, Wi, Wnl, Wor, Woi, out, counter, gamma, beta, out);
        hipLaunchKernelGGL(bnorm, dim3(CC), dim3(256), 0, stream, out, gamma, beta);
    }
}

// Round 6
// 212.175 us; speedup vs baseline: 1.0505x; 1.0505x over previous
//
#include <hip/hip_runtime.h>

#define BB 256
#define NN 4096
#define CC 16
#define WW 10
#define LL 4087  // N - W + 1
#define EPSF 1e-5f

// ---------------- Kernel 0: pack + zero-pad weights into ws (512 KB) ----------------
// pk[n*16+c] = {Wr[c,n], Wi[c,n]}, zeros for n >= LL
__global__ __launch_bounds__(256) void pack_weights(const float* __restrict__ Wr,
                                                    const float* __restrict__ Wi,
                                                    float2* __restrict__ pk) {
    int tg = blockIdx.x * 256 + threadIdx.x;  // [0, 65536)
    int n = tg >> 4, c = tg & 15;
    float2 v = make_float2(0.f, 0.f);
    if (n < LL) { v.x = Wr[c * LL + n]; v.y = Wi[c * LL + n]; }
    pk[tg] = v;
}

// ---------------- Kernel 1: fused stage1+2+3, one block per b, 1024 threads ----------------
// 1024 threads = 64 tc (n-chunks of 64) x 16 c. Rolling 16-slot weight window,
// x read exactly once as float2. 16 waves/CU = 4 waves/SIMD for latency hiding.
// NOTE (R3): float4/lane + nontemporal loads regressed (−11.6 us); keep float2, no nt.
// NOTE (R5): fusing BN via last-block finalizer regressed (−9.4 us); keep separate bnorm.
template <bool PK>
__global__ __launch_bounds__(1024) void fused_main(const float* __restrict__ x,
                                                   const float2* __restrict__ pk,
                                                   const float* __restrict__ Wr,
                                                   const float* __restrict__ Wi,
                                                   const float* __restrict__ Wnl,
                                                   const float* __restrict__ Wor,
                                                   const float* __restrict__ Woi,
                                                   float* __restrict__ outraw) {
    const int b = blockIdx.x;
    const int tid = threadIdx.x;
    const int tc = tid >> 4;   // 0..63
    const int c = tid & 15;
    const int n0 = tc * 64;

    const float2* __restrict__ x2 = (const float2*)x + (size_t)b * (NN * CC);

    float wr[16], wi[16];
    float fr[WW], fi[WW];
#pragma unroll
    for (int w = 0; w < WW; ++w) { fr[w] = 0.f; fi[w] = 0.f; }

    // prefill slots 15..7 with weights n0-1..n0-9 (zero if negative)
#pragma unroll
    for (int i = 1; i <= 9; ++i) {
        const int m = n0 - i;
        float vr = 0.f, vi = 0.f;
        if (PK) {
            if (m >= 0) { const float2 t = pk[m * 16 + c]; vr = t.x; vi = t.y; }
        } else {
            const int mc = m < 0 ? 0 : m;
            const float a = Wr[c * LL + mc], q = Wi[c * LL + mc];
            vr = (m >= 0) ? a : 0.f;
            vi = (m >= 0) ? q : 0.f;
        }
        wr[16 - i] = vr;
        wi[16 - i] = vi;
    }

#pragma unroll 1
    for (int g = 0; g < 4; ++g) {
        const int nb = n0 + g * 16;
#pragma unroll
        for (int p = 0; p < 16; ++p) {
            const int n = nb + p;
            float vr, vi;
            if (PK) {
                const float2 t = pk[n * 16 + c];
                vr = t.x; vi = t.y;
            } else {
                const int nc2 = (n < LL) ? n : (LL - 1);
                const float a = Wr[c * LL + nc2], q = Wi[c * LL + nc2];
                vr = (n < LL) ? a : 0.f;
                vi = (n < LL) ? q : 0.f;
            }
            const float2 xv = x2[n * 16 + c];
            wr[p] = vr;
            wi[p] = vi;
#pragma unroll
            for (int w = 0; w < WW; ++w) {
                fr[w] += xv.x * wr[(p - w) & 15];
                fi[w] += xv.y * wi[(p - w) & 15];
            }
        }
    }

    // reduce over tc: within a wave tc occupies lane bits 4..5 -> xor-reduce,
    // then 16 wave-partials via LDS.
#pragma unroll
    for (int w = 0; w < WW; ++w) {
        fr[w] += __shfl_xor(fr[w], 16);
        fr[w] += __shfl_xor(fr[w], 32);
        fi[w] += __shfl_xor(fi[w], 16);
        fi[w] += __shfl_xor(fi[w], 32);
    }
    __shared__ float red[16][320];
    __shared__ float F2[320];
    __shared__ float nls[320];
    const int lane = tid & 63, wave = tid >> 6;
    if (lane < 16) {  // lane == c for these lanes
#pragma unroll
        for (int w = 0; w < WW; ++w) {
            red[wave][lane * 20 + w] = fr[w];
            red[wave][lane * 20 + 10 + w] = fi[w];
        }
    }
    __syncthreads();
    if (tid < 320) {
        float s = 0.f;
#pragma unroll
        for (int k = 0; k < 16; ++k) s += red[k][tid];
        F2[tid] = s;  // slot = c*20 + j*10 + w  (j=0:real, 1:imag)
    }
    __syncthreads();
    // amplitude scaling
    if (tid < 160) {
        const int cc = tid / 10, w = tid % 10;
        const float a = F2[cc * 20 + w], q = F2[cc * 20 + 10 + w];
        const float amp = a * a + q * q;
        F2[cc * 20 + w] = a * amp;
        F2[cc * 20 + 10 + w] = q * amp;
    }
    __syncthreads();
    // nl[w,c,o] = sum_i tf[w,i] * Wnl[c,o,i]
    if (tid < 320) {
        const int cc = tid / 20, rem = tid % 20, o = rem / 10, w = rem % 10;
        const float* __restrict__ wn = Wnl + (cc * 2 + o) * 32;
        float acc = 0.f;
#pragma unroll
        for (int i = 0; i < 16; ++i) acc += F2[i * 20 + w] * wn[i];
#pragma unroll
        for (int i = 0; i < 16; ++i) acc += F2[i * 20 + 10 + w] * wn[16 + i];
        nls[tid] = acc;  // slot = c*20 + o*10 + w
    }
    __syncthreads();
    // out[b,c,o] = sum_w nl[w,c,o] * Wout_o[c,w]
    if (tid < 32) {
        const int cc = tid >> 1, o = tid & 1;
        const float* __restrict__ wo = (o == 0 ? Wor : Woi) + cc * WW;
        float acc = 0.f;
#pragma unroll
        for (int w = 0; w < WW; ++w) acc += nls[cc * 20 + o * 10 + w] * wo[w];
        outraw[b * 32 + cc * 2 + o] = acc;
    }
}

// ---------------- Kernel 2: BatchNorm in place on d_out ----------------
__global__ __launch_bounds__(256) void bnorm(float* __restrict__ out,
                                             const float* __restrict__ gamma,
                                             const float* __restrict__ beta) {
    const int c = blockIdx.x;   // [0,16)
    const int t = threadIdx.x;  // [0,256) == b
    const float v0 = out[t * 32 + c * 2 + 0];
    const float v1 = out[t * 32 + c * 2 + 1];
    float s = v0 + v1;
    float ss = v0 * v0 + v1 * v1;
#pragma unroll
    for (int off = 32; off > 0; off >>= 1) {
        s += __shfl_down(s, off, 64);
        ss += __shfl_down(ss, off, 64);
    }
    __shared__ float ls[8];
    const int wave = t >> 6, lane = t & 63;
    if (lane == 0) { ls[wave * 2] = s; ls[wave * 2 + 1] = ss; }
    __syncthreads();
    const float S = ls[0] + ls[2] + ls[4] + ls[6];
    const float SS = ls[1] + ls[3] + ls[5] + ls[7];
    const float mean = S * (1.f / 512.f);
    const float var = SS * (1.f / 512.f) - mean * mean;
    const float scale = gamma[c] * rsqrtf(var + EPSF);
    const float sh = beta[c];
    out[t * 32 + c * 2 + 0] = (v0 - mean) * scale + sh;
    out[t * 32 + c * 2 + 1] = (v1 - mean) * scale + sh;
}

extern "C" void kernel_launch(void* const* d_in, const int* in_sizes, int n_in,
                              void* d_out, int out_size, void* d_ws, size_t ws_size,
                              hipStream_t stream) {
    const float* x     = (const float*)d_in[0];
    const float* Wr    = (const float*)d_in[1];
    const float* Wi    = (const float*)d_in[2];
    const float* Wnl   = (const float*)d_in[3];
    const float* Wor   = (const float*)d_in[4];
    const float* Woi   = (const float*)d_in[5];
    const float* gamma = (const float*)d_in[6];
    const float* beta  = (const float*)d_in[7];
    float* out = (float*)d_out;

    const size_t pk_bytes = (size_t)NN * CC * sizeof(float2);  // 524288
    float2* pk = (float2*)d_ws;
    const bool use_pk = (ws_size >= pk_bytes);  // ws_size fixed -> same path every call

    if (use_pk) {
        hipLaunchKernelGGL(pack_weights, dim3(256), dim3(256), 0, stream, Wr, Wi, pk);
        hipLaunchKernelGGL((fused_main<true>), dim3(BB), dim3(1024), 0, stream,
                           x, pk, Wr, Wi, Wnl, Wor, Woi, out);
    } else {
        hipLaunchKernelGGL((fused_main<false>), dim3(BB), dim3(1024), 0, stream,
                           x, pk, Wr, Wi, Wnl, Wor, Woi, out);
    }
    hipLaunchKernelGGL(bnorm, dim3(CC), dim3(256), 0, stream, out, gamma, beta);
}